// Round 4
// baseline (2401.298 us; speedup 1.0000x reference)
//
#include <hip/hip_runtime.h>
#include <math.h>
#include <stdint.h>

#define BB 32
#define TT 1024
#define INF 256
#define HH 128
#define G4 512   // 4*H
#define CH 16    // LSTM steps per LDS chunk

typedef _Float16 half2_t __attribute__((ext_vector_type(2)));
typedef __attribute__((address_space(3))) uint32_t lds_u32;
typedef __attribute__((address_space(1))) const uint32_t glb_u32;

__device__ __forceinline__ float fdot2f(half2_t a, half2_t b, float c) {
    return __builtin_amdgcn_fdot2(a, b, c, false);
}
__device__ __forceinline__ float rcpf(float x) {
    return __builtin_amdgcn_rcpf(x);
}
// workgroup barrier that drains ONLY lgkmcnt (no vmcnt) — keeps async
// global_load_lds prefetch in flight across per-step barriers.
__device__ __forceinline__ void bar_lgkm() {
    asm volatile("s_waitcnt lgkmcnt(0)\n\ts_barrier" ::: "memory");
}

// =============== GEMM: C[m,n] = sum_k A[m,k]*W[n,k] + (bih[n]+bhh[n]) ===============
__global__ __launch_bounds__(256) void gemm_inproj(
    const float* __restrict__ A,        // 32768 x 256
    const float* __restrict__ w_ih_l,   // 2 x 512 x 256  (this layer's slice)
    const float* __restrict__ b_ih_l,   // 2 x 512
    const float* __restrict__ b_hh_l,   // 2 x 512
    float* __restrict__ xproj)          // 2 x 32768 x 512
{
    const int d  = blockIdx.z;
    const float* W = w_ih_l + (size_t)d * G4 * INF;
    float* C = xproj + (size_t)d * 32768 * 512;
    const int m0 = blockIdx.y * 64;
    const int n0 = blockIdx.x * 64;
    const int tid = threadIdx.x;
    const int tx = tid & 15, ty = tid >> 4;

    __shared__ __align__(16) float As[16 * 68];
    __shared__ __align__(16) float Bs[16 * 68];

    float acc[4][4] = {};
    const int lr = tid >> 2;        // 0..63 : row within tile for staging
    const int lk = (tid & 3) * 4;   // k offset for staging

    float4 a_cur = *(const float4*)(A + (size_t)(m0 + lr) * 256 + lk);
    float4 b_cur = *(const float4*)(W + (size_t)(n0 + lr) * 256 + lk);

    for (int k0 = 0; k0 < 256; k0 += 16) {
        __syncthreads();
        As[(lk + 0) * 68 + lr] = a_cur.x; As[(lk + 1) * 68 + lr] = a_cur.y;
        As[(lk + 2) * 68 + lr] = a_cur.z; As[(lk + 3) * 68 + lr] = a_cur.w;
        Bs[(lk + 0) * 68 + lr] = b_cur.x; Bs[(lk + 1) * 68 + lr] = b_cur.y;
        Bs[(lk + 2) * 68 + lr] = b_cur.z; Bs[(lk + 3) * 68 + lr] = b_cur.w;
        __syncthreads();
        if (k0 + 16 < 256) {
            a_cur = *(const float4*)(A + (size_t)(m0 + lr) * 256 + k0 + 16 + lk);
            b_cur = *(const float4*)(W + (size_t)(n0 + lr) * 256 + k0 + 16 + lk);
        }
#pragma unroll
        for (int kk = 0; kk < 16; ++kk) {
            float4 av = *(const float4*)&As[kk * 68 + ty * 4];
            float4 bv = *(const float4*)&Bs[kk * 68 + tx * 4];
            float ar[4] = {av.x, av.y, av.z, av.w};
            float br[4] = {bv.x, bv.y, bv.z, bv.w};
#pragma unroll
            for (int i = 0; i < 4; ++i)
#pragma unroll
                for (int j = 0; j < 4; ++j)
                    acc[i][j] += ar[i] * br[j];
        }
    }

    float bias[4];
#pragma unroll
    for (int j = 0; j < 4; ++j) {
        const int n = n0 + tx * 4 + j;
        bias[j] = b_ih_l[d * G4 + n] + b_hh_l[d * G4 + n];
    }
#pragma unroll
    for (int i = 0; i < 4; ++i) {
        float4 o;
        o.x = acc[i][0] + bias[0];
        o.y = acc[i][1] + bias[1];
        o.z = acc[i][2] + bias[2];
        o.w = acc[i][3] + bias[3];
        *(float4*)(C + (size_t)(m0 + ty * 4 + i) * 512 + n0 + tx * 4) = o;
    }
}

// =============== LSTM recurrence v4: k-sliced quads, DPP reduce ===============
// Lane l: s = l&3 (k-slice AND gate id), g = l>>2; pair index p = 16*wave + g.
// Quad (4 lanes) computes rows {gate G, j in {2p,2p+1}} over k-slices of 32.
// DPP butterfly (xor1,xor2) -> all lanes hold all 8 preacts; lane s activates
// gate s; xor2 pairs i*g and routes sig(o); xor1 delivers to c-owner (s==1).
__global__ __launch_bounds__(256, 1) void lstm_rec(
    const float* __restrict__ xproj,   // 2 x B x T x 512
    const float* __restrict__ w_hh_l,  // 2 x 512 x 128 (this layer's slice)
    float* __restrict__ out)           // B x T x 256  ([fwd|bwd] concat)
{
    const int b = blockIdx.x & 31;
    const int d = blockIdx.x >> 5;
    const int tid = threadIdx.x;
    const int wvid = tid >> 6;
    const int l = tid & 63;
    const int s = l & 3;              // k-slice / gate id
    const int g = l >> 2;             // 0..15
    const int p = (wvid << 4) | g;    // 0..63 ; j0 = 2p, j1 = 2p+1

    __shared__ __align__(16) _Float16 hs[HH];            // h in f16
    __shared__ __align__(16) float xbuf[2][CH * 512];    // 2 x 32 KB staged x
    __shared__ __align__(16) float obuf[CH * HH];        // 8 KB h output buffer

    // ---- weights: rows r=2G+jj -> gate-row 128G+2p+jj, k in [32s,32s+32), f16 ----
    half2_t wv[8][16];
#pragma unroll
    for (int G = 0; G < 4; ++G)
#pragma unroll
        for (int jj = 0; jj < 2; ++jj) {
            const float* wr = w_hh_l + (size_t)(d * G4 + 128 * G + 2 * p + jj) * HH + 32 * s;
            const int r = 2 * G + jj;
#pragma unroll
            for (int q4 = 0; q4 < 8; ++q4) {
                float4 f = *(const float4*)(wr + 4 * q4);
                half2_t lo = {(_Float16)f.x, (_Float16)f.y};
                half2_t hi = {(_Float16)f.z, (_Float16)f.w};
                wv[r][2 * q4]     = lo;
                wv[r][2 * q4 + 1] = hi;
            }
        }

    if (tid < 64) ((half2_t*)hs)[tid] = half2_t{(_Float16)0.f, (_Float16)0.f};
    float c0 = 0.f, c1 = 0.f;

    const float* xp = xproj + ((size_t)d * BB + b) * TT * 512;
    float* ob = out + (size_t)b * TT * 256 + d * HH;

    // ---- stage chunk 0 into buf 0 via async global->LDS ----
    {
        const int tlo = d ? 1008 : 0;
        const float* gsrc = xp + (size_t)tlo * 512;
#pragma unroll
        for (int i = 0; i < 8; ++i)
            __builtin_amdgcn_global_load_lds((glb_u32*)(gsrc + tid * 4 + i * 1024),
                                             (lds_u32*)&xbuf[0][tid * 4 + i * 1024],
                                             16, 0, 0);
    }
    __syncthreads();   // drains vmcnt -> buf0 ready; hs init visible

    for (int ck = 0; ck < 64; ++ck) {
        const int cur = ck & 1;
        // async prefetch next chunk into the other buffer (stays in flight
        // across the per-step lgkm-only barriers)
        if (ck + 1 < 64) {
            const int tlo = d ? (1008 - (ck + 1) * CH) : (ck + 1) * CH;
            const float* gsrc = xp + (size_t)tlo * 512;
#pragma unroll
            for (int i = 0; i < 8; ++i)
                __builtin_amdgcn_global_load_lds((glb_u32*)(gsrc + tid * 4 + i * 1024),
                                                 (lds_u32*)&xbuf[cur ^ 1][tid * 4 + i * 1024],
                                                 16, 0, 0);
        }
        const float* xb = xbuf[cur];

#pragma unroll 1
        for (int si = 0; si < CH; ++si) {
            const int lds_t = d ? (CH - 1 - si) : si;

            // h slice: 64 B (h[32s .. 32s+32)) as 4 x b128
            const float4* hp = (const float4*)(hs + 32 * s);
            float4 hA = hp[0], hB = hp[1], hC = hp[2], hD = hp[3];
            half2_t hh[16];
            hh[0]  = __builtin_bit_cast(half2_t, hA.x);
            hh[1]  = __builtin_bit_cast(half2_t, hA.y);
            hh[2]  = __builtin_bit_cast(half2_t, hA.z);
            hh[3]  = __builtin_bit_cast(half2_t, hA.w);
            hh[4]  = __builtin_bit_cast(half2_t, hB.x);
            hh[5]  = __builtin_bit_cast(half2_t, hB.y);
            hh[6]  = __builtin_bit_cast(half2_t, hB.z);
            hh[7]  = __builtin_bit_cast(half2_t, hB.w);
            hh[8]  = __builtin_bit_cast(half2_t, hC.x);
            hh[9]  = __builtin_bit_cast(half2_t, hC.y);
            hh[10] = __builtin_bit_cast(half2_t, hC.z);
            hh[11] = __builtin_bit_cast(half2_t, hC.w);
            hh[12] = __builtin_bit_cast(half2_t, hD.x);
            hh[13] = __builtin_bit_cast(half2_t, hD.y);
            hh[14] = __builtin_bit_cast(half2_t, hD.z);
            hh[15] = __builtin_bit_cast(half2_t, hD.w);

            float a[8] = {0.f, 0.f, 0.f, 0.f, 0.f, 0.f, 0.f, 0.f};
#pragma unroll
            for (int r = 0; r < 8; ++r)
#pragma unroll
                for (int kk = 0; kk < 16; ++kk)
                    a[r] = fdot2f(wv[r][kk], hh[kk], a[r]);

            // quad butterfly over k-slices: all lanes get full sums of 8 rows
#pragma unroll
            for (int r = 0; r < 8; ++r) {
                a[r] += __shfl_xor(a[r], 1, 64);
                a[r] += __shfl_xor(a[r], 2, 64);
            }

            // add x-preacts for this lane's gate (rows 128s+2p, +1)
            const float2 xv = *(const float2*)&xb[lds_t * 512 + 128 * s + 2 * p];
            float p0 = (s == 0 ? a[0] : s == 1 ? a[2] : s == 2 ? a[4] : a[6]) + xv.x;
            float p1 = (s == 0 ? a[1] : s == 1 ? a[3] : s == 2 ? a[5] : a[7]) + xv.y;

            // activation: gate s (0:i sig, 1:f sig, 2:g tanh, 3:o sig)
            const bool isG = (s == 2);
            const float e0 = __expf(isG ? 2.f * p0 : -p0);
            const float r0 = rcpf(1.f + e0);
            const float v0 = isG ? 1.f - 2.f * r0 : r0;
            const float e1 = __expf(isG ? 2.f * p1 : -p1);
            const float r1 = rcpf(1.f + e1);
            const float v1 = isG ? 1.f - 2.f * r1 : r1;

            // xor2: s=0 gets tanh(g); s=1 gets sig(o)
            const float t0 = __shfl_xor(v0, 2, 64);
            const float t1 = __shfl_xor(v1, 2, 64);
            // xor1: s=1 gets sig(i)*tanh(g) from s=0
            const float u0 = __shfl_xor(v0 * t0, 1, 64);
            const float u1 = __shfl_xor(v1 * t1, 1, 64);

            if (s == 1) {   // c-owner: v=sig(f), t=sig(o), u=sig(i)*tanh(g)
                c0 = v0 * c0 + u0;
                c1 = v1 * c1 + u1;
                const float th0 = 1.f - 2.f * rcpf(1.f + __expf(2.f * c0));
                const float th1 = 1.f - 2.f * rcpf(1.f + __expf(2.f * c1));
                const float h0 = t0 * th0;
                const float h1 = t1 * th1;
                half2_t hpk = {(_Float16)h0, (_Float16)h1};
                ((half2_t*)hs)[p] = hpk;
                *(float2*)&obuf[si * HH + 2 * p] = make_float2(h0, h1);
            }
            bar_lgkm();   // lgkmcnt-only barrier: prefetch stays in flight
        }

        // flush obuf for chunk ck (coalesced)
        {
            const int idx = tid * 8;
            const int sf = idx >> 7, jf = idx & 127;
            const int sg = ck * CH + sf;
            const int t  = d ? (TT - 1 - sg) : sg;
            float4 o0 = *(const float4*)&obuf[idx];
            float4 o1 = *(const float4*)&obuf[idx + 4];
            *(float4*)&ob[(size_t)t * 256 + jf]     = o0;
            *(float4*)&ob[(size_t)t * 256 + jf + 4] = o1;
        }
        __syncthreads();   // full drain: next-chunk data arrived, obuf reads done
    }
}

// =============== Attention (last-row only) + FC ===============
__global__ __launch_bounds__(256) void attn_kernel(
    const float* __restrict__ out1,  // B x T x 256
    const float* __restrict__ wq, const float* __restrict__ bq,
    const float* __restrict__ wk,
    const float* __restrict__ wv, const float* __restrict__ bv,
    const float* __restrict__ wfc, const float* __restrict__ bfc,
    float* __restrict__ outp)        // B x 4
{
    const int b = blockIdx.x;
    const int tid = threadIdx.x;
    __shared__ float xl[256], q[256], u[256], cx[256];
    __shared__ __align__(16) float r[256];
    __shared__ float sc[TT];
    __shared__ float red[256];

    const float* ob = out1 + (size_t)b * TT * 256;

    xl[tid] = ob[(size_t)(TT - 1) * 256 + tid];
    __syncthreads();

    float acc = bq[tid];
    const float* wqr = wq + (size_t)tid * 256;
#pragma unroll 4
    for (int k = 0; k < 256; ++k) acc += xl[k] * wqr[k];
    q[tid] = acc;
    __syncthreads();

    acc = 0.f;
#pragma unroll 4
    for (int dd = 0; dd < 256; ++dd) acc += q[dd] * wk[(size_t)dd * 256 + tid];
    r[tid] = acc;
    __syncthreads();

    const int wave = tid >> 6, lane = tid & 63;
    float4 r4 = *(const float4*)&r[lane * 4];
    for (int t = wave; t < TT; t += 4) {
        float4 o4 = *(const float4*)(ob + (size_t)t * 256 + lane * 4);
        float p = r4.x * o4.x + r4.y * o4.y + r4.z * o4.z + r4.w * o4.w;
#pragma unroll
        for (int off = 32; off > 0; off >>= 1) p += __shfl_down(p, off, 64);
        if (lane == 0) sc[t] = p * 0.0625f;
    }
    __syncthreads();

    float mx = -1e30f;
#pragma unroll
    for (int i = 0; i < 4; ++i) mx = fmaxf(mx, sc[tid + 256 * i]);
    red[tid] = mx; __syncthreads();
    for (int st = 128; st > 0; st >>= 1) {
        if (tid < st) red[tid] = fmaxf(red[tid], red[tid + st]);
        __syncthreads();
    }
    mx = red[0]; __syncthreads();
    float lsum = 0.f;
#pragma unroll
    for (int i = 0; i < 4; ++i) {
        float e = expf(sc[tid + 256 * i] - mx);
        sc[tid + 256 * i] = e;
        lsum += e;
    }
    __syncthreads();
    red[tid] = lsum; __syncthreads();
    for (int st = 128; st > 0; st >>= 1) {
        if (tid < st) red[tid] += red[tid + st];
        __syncthreads();
    }
    const float inv = 1.f / red[0];
    __syncthreads();

    acc = 0.f;
#pragma unroll 8
    for (int t = 0; t < TT; ++t) acc += sc[t] * ob[(size_t)t * 256 + tid];
    u[tid] = acc * inv;
    __syncthreads();

    acc = bv[tid];
#pragma unroll 4
    for (int k = 0; k < 256; ++k) acc += u[k] * wv[(size_t)tid * 256 + k];
    cx[tid] = acc;
    __syncthreads();

    if (tid < 4) {
        float o = bfc[tid];
        for (int k = 0; k < 256; ++k) o += cx[k] * wfc[tid * 256 + k];
        outp[b * 4 + tid] = o;
    }
}

extern "C" void kernel_launch(void* const* d_in, const int* in_sizes, int n_in,
                              void* d_out, int out_size, void* d_ws, size_t ws_size,
                              hipStream_t stream)
{
    const float* x    = (const float*)d_in[0];
    const float* w_ih = (const float*)d_in[1];
    const float* w_hh = (const float*)d_in[2];
    const float* b_ih = (const float*)d_in[3];
    const float* b_hh = (const float*)d_in[4];
    const float* wq   = (const float*)d_in[5];
    const float* wk   = (const float*)d_in[6];
    const float* wv   = (const float*)d_in[7];
    const float* bq   = (const float*)d_in[8];
    const float* bv   = (const float*)d_in[10];
    const float* wfc  = (const float*)d_in[11];
    const float* bfcv = (const float*)d_in[12];
    float* outp = (float*)d_out;

    float* ws    = (float*)d_ws;
    float* xproj = ws;                        // 2*32768*512 floats (128 MB)
    float* out0  = ws + 33554432;             // 8,388,608 floats (32 MB)
    float* out1  = out0 + 8388608;            // 8,388,608 floats (32 MB)

    dim3 gg(8, 512, 2);

    gemm_inproj<<<gg, 256, 0, stream>>>(x, w_ih, b_ih, b_hh, xproj);
    lstm_rec<<<64, 256, 0, stream>>>(xproj, w_hh, out0);
    gemm_inproj<<<gg, 256, 0, stream>>>(out0, w_ih + 2 * 512 * 256, b_ih + 1024, b_hh + 1024, xproj);
    lstm_rec<<<64, 256, 0, stream>>>(xproj, w_hh + 2 * 512 * 128, out1);
    attn_kernel<<<32, 256, 0, stream>>>(out1, wq, bq, wk, wv, bv, wfc, bfcv, outp);
}

// Round 5
// 2127.531 us; speedup vs baseline: 1.1287x; 1.1287x over previous
//
#include <hip/hip_runtime.h>
#include <math.h>
#include <stdint.h>

#define BB 32
#define TT 1024
#define INF 256
#define HH 128
#define G4 512   // 4*H
#define CH 16    // LSTM steps per LDS chunk

typedef _Float16 half2_t __attribute__((ext_vector_type(2)));
typedef __attribute__((address_space(3))) uint32_t lds_u32;
typedef __attribute__((address_space(1))) const uint32_t glb_u32;

__device__ __forceinline__ float fdot2f(half2_t a, half2_t b, float c) {
    return __builtin_amdgcn_fdot2(a, b, c, false);
}
__device__ __forceinline__ float rcpf(float x) {
    return __builtin_amdgcn_rcpf(x);
}
// quad_perm DPP moves: VALU pipe, no LDS traffic (unlike __shfl_xor -> ds_bpermute)
__device__ __forceinline__ float dpp_xor1(float x) {   // lanes 0<->1, 2<->3 in quad
    return __builtin_bit_cast(float, __builtin_amdgcn_update_dpp(
        0, __builtin_bit_cast(int, x), 0xB1, 0xF, 0xF, true));
}
__device__ __forceinline__ float dpp_xor2(float x) {   // lanes 0<->2, 1<->3 in quad
    return __builtin_bit_cast(float, __builtin_amdgcn_update_dpp(
        0, __builtin_bit_cast(int, x), 0x4E, 0xF, 0xF, true));
}
// workgroup barrier that drains ONLY lgkmcnt (no vmcnt) — keeps async
// global_load_lds prefetch in flight across per-step barriers.
__device__ __forceinline__ void bar_lgkm() {
    asm volatile("s_waitcnt lgkmcnt(0)\n\ts_barrier" ::: "memory");
}

// =============== GEMM: C[m,n] = sum_k A[m,k]*W[n,k] + (bih[n]+bhh[n]) ===============
// BK=32: the 32-kk FMA block (~1024 cyc) exceeds HBM latency (~900), so the
// next tile's loads (issued right after the staging barrier) are covered.
__global__ __launch_bounds__(256) void gemm_inproj(
    const float* __restrict__ A,        // 32768 x 256
    const float* __restrict__ w_ih_l,   // 2 x 512 x 256  (this layer's slice)
    const float* __restrict__ b_ih_l,   // 2 x 512
    const float* __restrict__ b_hh_l,   // 2 x 512
    float* __restrict__ xproj)          // 2 x 32768 x 512
{
    const int d  = blockIdx.z;
    const float* W = w_ih_l + (size_t)d * G4 * INF;
    float* C = xproj + (size_t)d * 32768 * 512;
    const int m0 = blockIdx.y * 64;
    const int n0 = blockIdx.x * 64;
    const int tid = threadIdx.x;
    const int tx = tid & 15, ty = tid >> 4;

    __shared__ __align__(16) float As[32 * 69];
    __shared__ __align__(16) float Bs[32 * 69];

    float acc[4][4] = {};
    const int lr = tid >> 2;        // 0..63 : row within tile for staging
    const int lk = (tid & 3) * 8;   // k offset for staging (8 floats/thread)

    float4 a0 = *(const float4*)(A + (size_t)(m0 + lr) * 256 + lk);
    float4 a1 = *(const float4*)(A + (size_t)(m0 + lr) * 256 + lk + 4);
    float4 b0 = *(const float4*)(W + (size_t)(n0 + lr) * 256 + lk);
    float4 b1 = *(const float4*)(W + (size_t)(n0 + lr) * 256 + lk + 4);

    for (int k0 = 0; k0 < 256; k0 += 32) {
        __syncthreads();
        As[(lk + 0) * 69 + lr] = a0.x; As[(lk + 1) * 69 + lr] = a0.y;
        As[(lk + 2) * 69 + lr] = a0.z; As[(lk + 3) * 69 + lr] = a0.w;
        As[(lk + 4) * 69 + lr] = a1.x; As[(lk + 5) * 69 + lr] = a1.y;
        As[(lk + 6) * 69 + lr] = a1.z; As[(lk + 7) * 69 + lr] = a1.w;
        Bs[(lk + 0) * 69 + lr] = b0.x; Bs[(lk + 1) * 69 + lr] = b0.y;
        Bs[(lk + 2) * 69 + lr] = b0.z; Bs[(lk + 3) * 69 + lr] = b0.w;
        Bs[(lk + 4) * 69 + lr] = b1.x; Bs[(lk + 5) * 69 + lr] = b1.y;
        Bs[(lk + 6) * 69 + lr] = b1.z; Bs[(lk + 7) * 69 + lr] = b1.w;
        __syncthreads();
        if (k0 + 32 < 256) {   // in flight during the 32-kk FMA block
            a0 = *(const float4*)(A + (size_t)(m0 + lr) * 256 + k0 + 32 + lk);
            a1 = *(const float4*)(A + (size_t)(m0 + lr) * 256 + k0 + 32 + lk + 4);
            b0 = *(const float4*)(W + (size_t)(n0 + lr) * 256 + k0 + 32 + lk);
            b1 = *(const float4*)(W + (size_t)(n0 + lr) * 256 + k0 + 32 + lk + 4);
        }
#pragma unroll
        for (int kk = 0; kk < 32; ++kk) {
            float4 av = *(const float4*)&As[kk * 69 + ty * 4];
            float4 bv = *(const float4*)&Bs[kk * 69 + tx * 4];
            float ar[4] = {av.x, av.y, av.z, av.w};
            float br[4] = {bv.x, bv.y, bv.z, bv.w};
#pragma unroll
            for (int i = 0; i < 4; ++i)
#pragma unroll
                for (int j = 0; j < 4; ++j)
                    acc[i][j] += ar[i] * br[j];
        }
    }

    float bias[4];
#pragma unroll
    for (int j = 0; j < 4; ++j) {
        const int n = n0 + tx * 4 + j;
        bias[j] = b_ih_l[d * G4 + n] + b_hh_l[d * G4 + n];
    }
#pragma unroll
    for (int i = 0; i < 4; ++i) {
        float4 o;
        o.x = acc[i][0] + bias[0];
        o.y = acc[i][1] + bias[1];
        o.z = acc[i][2] + bias[2];
        o.w = acc[i][3] + bias[3];
        *(float4*)(C + (size_t)(m0 + ty * 4 + i) * 512 + n0 + tx * 4) = o;
    }
}

// =============== LSTM recurrence v5: k-sliced quads, DPP reduce ===============
// Lane l: s = l&3 (k-slice AND gate id), g = l>>2; pair index p = 16*wave + g.
// Quad (4 lanes) computes rows {gate G, j in {2p,2p+1}} over k-slices of 32.
// DPP quad_perm butterfly -> all lanes hold full sums of 8 rows; lane s
// activates gate s; DPP xor2 pairs i*g and routes sig(o); DPP xor1 delivers
// to the c-owner lane (s==1). Zero LDS in the gate-combine path.
__global__ __launch_bounds__(256, 1) void lstm_rec(
    const float* __restrict__ xproj,   // 2 x B x T x 512
    const float* __restrict__ w_hh_l,  // 2 x 512 x 128 (this layer's slice)
    float* __restrict__ out)           // B x T x 256  ([fwd|bwd] concat)
{
    const int b = blockIdx.x & 31;
    const int d = blockIdx.x >> 5;
    const int tid = threadIdx.x;
    const int wvid = tid >> 6;
    const int l = tid & 63;
    const int s = l & 3;              // k-slice / gate id
    const int g = l >> 2;             // 0..15
    const int p = (wvid << 4) | g;    // 0..63 ; j0 = 2p, j1 = 2p+1

    __shared__ __align__(16) _Float16 hs[HH];            // h in f16
    __shared__ __align__(16) float xbuf[2][CH * 512];    // 2 x 32 KB staged x
    __shared__ __align__(16) float obuf[CH * HH];        // 8 KB h output buffer

    // ---- weights: rows r=2G+jj -> gate-row 128G+2p+jj, k in [32s,32s+32), f16 ----
    half2_t wv[8][16];
#pragma unroll
    for (int G = 0; G < 4; ++G)
#pragma unroll
        for (int jj = 0; jj < 2; ++jj) {
            const float* wr = w_hh_l + (size_t)(d * G4 + 128 * G + 2 * p + jj) * HH + 32 * s;
            const int r = 2 * G + jj;
#pragma unroll
            for (int q4 = 0; q4 < 8; ++q4) {
                float4 f = *(const float4*)(wr + 4 * q4);
                half2_t lo = {(_Float16)f.x, (_Float16)f.y};
                half2_t hi = {(_Float16)f.z, (_Float16)f.w};
                wv[r][2 * q4]     = lo;
                wv[r][2 * q4 + 1] = hi;
            }
        }

    if (tid < 64) ((half2_t*)hs)[tid] = half2_t{(_Float16)0.f, (_Float16)0.f};
    float c0 = 0.f, c1 = 0.f;

    const float* xp = xproj + ((size_t)d * BB + b) * TT * 512;
    float* ob = out + (size_t)b * TT * 256 + d * HH;

    // ---- stage chunk 0 into buf 0 via async global->LDS ----
    {
        const int tlo = d ? 1008 : 0;
        const float* gsrc = xp + (size_t)tlo * 512;
#pragma unroll
        for (int i = 0; i < 8; ++i)
            __builtin_amdgcn_global_load_lds((glb_u32*)(gsrc + tid * 4 + i * 1024),
                                             (lds_u32*)&xbuf[0][tid * 4 + i * 1024],
                                             16, 0, 0);
    }
    __syncthreads();   // drains vmcnt -> buf0 ready; hs init visible

    for (int ck = 0; ck < 64; ++ck) {
        const int cur = ck & 1;
        // async prefetch next chunk into the other buffer (stays in flight
        // across the per-step lgkm-only barriers)
        if (ck + 1 < 64) {
            const int tlo = d ? (1008 - (ck + 1) * CH) : (ck + 1) * CH;
            const float* gsrc = xp + (size_t)tlo * 512;
#pragma unroll
            for (int i = 0; i < 8; ++i)
                __builtin_amdgcn_global_load_lds((glb_u32*)(gsrc + tid * 4 + i * 1024),
                                                 (lds_u32*)&xbuf[cur ^ 1][tid * 4 + i * 1024],
                                                 16, 0, 0);
        }
        const float* xb = xbuf[cur];

#pragma unroll 1
        for (int si = 0; si < CH; ++si) {
            const int lds_t = d ? (CH - 1 - si) : si;

            // h slice: 64 B (h[32s .. 32s+32)) as 4 x b128
            const float4* hp = (const float4*)(hs + 32 * s);
            float4 hA = hp[0], hB = hp[1], hC = hp[2], hD = hp[3];
            half2_t hh[16];
            hh[0]  = __builtin_bit_cast(half2_t, hA.x);
            hh[1]  = __builtin_bit_cast(half2_t, hA.y);
            hh[2]  = __builtin_bit_cast(half2_t, hA.z);
            hh[3]  = __builtin_bit_cast(half2_t, hA.w);
            hh[4]  = __builtin_bit_cast(half2_t, hB.x);
            hh[5]  = __builtin_bit_cast(half2_t, hB.y);
            hh[6]  = __builtin_bit_cast(half2_t, hB.z);
            hh[7]  = __builtin_bit_cast(half2_t, hB.w);
            hh[8]  = __builtin_bit_cast(half2_t, hC.x);
            hh[9]  = __builtin_bit_cast(half2_t, hC.y);
            hh[10] = __builtin_bit_cast(half2_t, hC.z);
            hh[11] = __builtin_bit_cast(half2_t, hC.w);
            hh[12] = __builtin_bit_cast(half2_t, hD.x);
            hh[13] = __builtin_bit_cast(half2_t, hD.y);
            hh[14] = __builtin_bit_cast(half2_t, hD.z);
            hh[15] = __builtin_bit_cast(half2_t, hD.w);

            float a[8] = {0.f, 0.f, 0.f, 0.f, 0.f, 0.f, 0.f, 0.f};
#pragma unroll
            for (int r = 0; r < 8; ++r)
#pragma unroll
                for (int kk = 0; kk < 16; ++kk)
                    a[r] = fdot2f(wv[r][kk], hh[kk], a[r]);

            // quad butterfly over k-slices via DPP (VALU pipe, no LDS)
#pragma unroll
            for (int r = 0; r < 8; ++r) {
                a[r] += dpp_xor1(a[r]);
                a[r] += dpp_xor2(a[r]);
            }

            // add x-preacts for this lane's gate (rows 128s+2p, +1)
            const float2 xv = *(const float2*)&xb[lds_t * 512 + 128 * s + 2 * p];
            float p0 = (s == 0 ? a[0] : s == 1 ? a[2] : s == 2 ? a[4] : a[6]) + xv.x;
            float p1 = (s == 0 ? a[1] : s == 1 ? a[3] : s == 2 ? a[5] : a[7]) + xv.y;

            // activation: gate s (0:i sig, 1:f sig, 2:g tanh, 3:o sig)
            const bool isG = (s == 2);
            const float e0 = __expf(isG ? 2.f * p0 : -p0);
            const float r0 = rcpf(1.f + e0);
            const float v0 = isG ? 1.f - 2.f * r0 : r0;
            const float e1 = __expf(isG ? 2.f * p1 : -p1);
            const float r1 = rcpf(1.f + e1);
            const float v1 = isG ? 1.f - 2.f * r1 : r1;

            // DPP xor2: s=0 gets tanh(g); s=1 gets sig(o)
            const float t0 = dpp_xor2(v0);
            const float t1 = dpp_xor2(v1);
            // DPP xor1: s=1 gets sig(i)*tanh(g) from s=0
            const float u0 = dpp_xor1(v0 * t0);
            const float u1 = dpp_xor1(v1 * t1);

            if (s == 1) {   // c-owner: v=sig(f), t=sig(o), u=sig(i)*tanh(g)
                c0 = v0 * c0 + u0;
                c1 = v1 * c1 + u1;
                const float th0 = 1.f - 2.f * rcpf(1.f + __expf(2.f * c0));
                const float th1 = 1.f - 2.f * rcpf(1.f + __expf(2.f * c1));
                const float h0 = t0 * th0;
                const float h1 = t1 * th1;
                half2_t hpk = {(_Float16)h0, (_Float16)h1};
                ((half2_t*)hs)[p] = hpk;
                *(float2*)&obuf[si * HH + 2 * p] = make_float2(h0, h1);
            }
            bar_lgkm();   // lgkmcnt-only barrier: prefetch stays in flight
        }

        // flush obuf for chunk ck (coalesced)
        {
            const int idx = tid * 8;
            const int sf = idx >> 7, jf = idx & 127;
            const int sg = ck * CH + sf;
            const int t  = d ? (TT - 1 - sg) : sg;
            float4 o0 = *(const float4*)&obuf[idx];
            float4 o1 = *(const float4*)&obuf[idx + 4];
            *(float4*)&ob[(size_t)t * 256 + jf]     = o0;
            *(float4*)&ob[(size_t)t * 256 + jf + 4] = o1;
        }
        __syncthreads();   // full drain: next-chunk data arrived, obuf reads done
    }
}

// =============== Attention (last-row only) + FC ===============
__global__ __launch_bounds__(256) void attn_kernel(
    const float* __restrict__ out1,  // B x T x 256
    const float* __restrict__ wq, const float* __restrict__ bq,
    const float* __restrict__ wk,
    const float* __restrict__ wv, const float* __restrict__ bv,
    const float* __restrict__ wfc, const float* __restrict__ bfc,
    float* __restrict__ outp)        // B x 4
{
    const int b = blockIdx.x;
    const int tid = threadIdx.x;
    __shared__ float xl[256], q[256], u[256], cx[256];
    __shared__ __align__(16) float r[256];
    __shared__ float sc[TT];
    __shared__ float red[256];

    const float* ob = out1 + (size_t)b * TT * 256;

    xl[tid] = ob[(size_t)(TT - 1) * 256 + tid];
    __syncthreads();

    float acc = bq[tid];
    const float* wqr = wq + (size_t)tid * 256;
#pragma unroll 4
    for (int k = 0; k < 256; ++k) acc += xl[k] * wqr[k];
    q[tid] = acc;
    __syncthreads();

    acc = 0.f;
#pragma unroll 4
    for (int dd = 0; dd < 256; ++dd) acc += q[dd] * wk[(size_t)dd * 256 + tid];
    r[tid] = acc;
    __syncthreads();

    const int wave = tid >> 6, lane = tid & 63;
    float4 r4 = *(const float4*)&r[lane * 4];
    for (int t = wave; t < TT; t += 4) {
        float4 o4 = *(const float4*)(ob + (size_t)t * 256 + lane * 4);
        float p = r4.x * o4.x + r4.y * o4.y + r4.z * o4.z + r4.w * o4.w;
#pragma unroll
        for (int off = 32; off > 0; off >>= 1) p += __shfl_down(p, off, 64);
        if (lane == 0) sc[t] = p * 0.0625f;
    }
    __syncthreads();

    float mx = -1e30f;
#pragma unroll
    for (int i = 0; i < 4; ++i) mx = fmaxf(mx, sc[tid + 256 * i]);
    red[tid] = mx; __syncthreads();
    for (int st = 128; st > 0; st >>= 1) {
        if (tid < st) red[tid] = fmaxf(red[tid], red[tid + st]);
        __syncthreads();
    }
    mx = red[0]; __syncthreads();
    float lsum = 0.f;
#pragma unroll
    for (int i = 0; i < 4; ++i) {
        float e = expf(sc[tid + 256 * i] - mx);
        sc[tid + 256 * i] = e;
        lsum += e;
    }
    __syncthreads();
    red[tid] = lsum; __syncthreads();
    for (int st = 128; st > 0; st >>= 1) {
        if (tid < st) red[tid] += red[tid + st];
        __syncthreads();
    }
    const float inv = 1.f / red[0];
    __syncthreads();

    acc = 0.f;
#pragma unroll 8
    for (int t = 0; t < TT; ++t) acc += sc[t] * ob[(size_t)t * 256 + tid];
    u[tid] = acc * inv;
    __syncthreads();

    acc = bv[tid];
#pragma unroll 4
    for (int k = 0; k < 256; ++k) acc += u[k] * wv[(size_t)tid * 256 + k];
    cx[tid] = acc;
    __syncthreads();

    if (tid < 4) {
        float o = bfc[tid];
        for (int k = 0; k < 256; ++k) o += cx[k] * wfc[tid * 256 + k];
        outp[b * 4 + tid] = o;
    }
}

extern "C" void kernel_launch(void* const* d_in, const int* in_sizes, int n_in,
                              void* d_out, int out_size, void* d_ws, size_t ws_size,
                              hipStream_t stream)
{
    const float* x    = (const float*)d_in[0];
    const float* w_ih = (const float*)d_in[1];
    const float* w_hh = (const float*)d_in[2];
    const float* b_ih = (const float*)d_in[3];
    const float* b_hh = (const float*)d_in[4];
    const float* wq   = (const float*)d_in[5];
    const float* wk   = (const float*)d_in[6];
    const float* wv   = (const float*)d_in[7];
    const float* bq   = (const float*)d_in[8];
    const float* bv   = (const float*)d_in[10];
    const float* wfc  = (const float*)d_in[11];
    const float* bfcv = (const float*)d_in[12];
    float* outp = (float*)d_out;

    float* ws    = (float*)d_ws;
    float* xproj = ws;                        // 2*32768*512 floats (128 MB)
    float* out0  = ws + 33554432;             // 8,388,608 floats (32 MB)
    float* out1  = out0 + 8388608;            // 8,388,608 floats (32 MB)

    dim3 gg(8, 512, 2);

    gemm_inproj<<<gg, 256, 0, stream>>>(x, w_ih, b_ih, b_hh, xproj);
    lstm_rec<<<64, 256, 0, stream>>>(xproj, w_hh, out0);
    gemm_inproj<<<gg, 256, 0, stream>>>(out0, w_ih + 2 * 512 * 256, b_ih + 1024, b_hh + 1024, xproj);
    lstm_rec<<<64, 256, 0, stream>>>(xproj, w_hh + 2 * 512 * 128, out1);
    attn_kernel<<<32, 256, 0, stream>>>(out1, wq, bq, wk, wv, bv, wfc, bfcv, outp);
}

// Round 6
// 1901.091 us; speedup vs baseline: 1.2631x; 1.1191x over previous
//
#include <hip/hip_runtime.h>
#include <math.h>
#include <stdint.h>

#define BB 32
#define TT 1024
#define INF 256
#define HH 128
#define G4 512   // 4*H
#define CH 16    // LSTM steps per LDS chunk

typedef _Float16 half2_t __attribute__((ext_vector_type(2)));
typedef __attribute__((address_space(3))) uint32_t lds_u32;
typedef __attribute__((address_space(1))) const uint32_t glb_u32;

__device__ __forceinline__ float fdot2f(half2_t a, half2_t b, float c) {
    return __builtin_amdgcn_fdot2(a, b, c, false);
}
__device__ __forceinline__ float rcpf(float x) {
    return __builtin_amdgcn_rcpf(x);
}
// quad_perm DPP moves: VALU pipe, no LDS traffic
__device__ __forceinline__ float dpp_xor1(float x) {   // lanes 0<->1, 2<->3 in quad
    return __builtin_bit_cast(float, __builtin_amdgcn_update_dpp(
        0, __builtin_bit_cast(int, x), 0xB1, 0xF, 0xF, true));
}
__device__ __forceinline__ float dpp_xor2(float x) {   // lanes 0<->2, 1<->3 in quad
    return __builtin_bit_cast(float, __builtin_amdgcn_update_dpp(
        0, __builtin_bit_cast(int, x), 0x4E, 0xF, 0xF, true));
}
// workgroup barrier draining ONLY lgkmcnt — keeps async global->LDS prefetch in flight
__device__ __forceinline__ void bar_lgkm() {
    asm volatile("s_waitcnt lgkmcnt(0)\n\ts_barrier" ::: "memory");
}

// =============== GEMM v6: 128x128 tile, BK=16, 8x8 micro-tile ===============
// 8x8 per thread as four 4x4 quadrants (row/col offsets +64): 4 ds_read_b128
// per 64 FMA -> VALU-bound, not LDS-pipe-bound. Next K-tile loads issued
// right after the staging barrier; 16-kk FMA block hides them.
__global__ __launch_bounds__(256) void gemm_inproj(
    const float* __restrict__ A,        // 32768 x 256
    const float* __restrict__ w_ih_l,   // 2 x 512 x 256  (this layer's slice)
    const float* __restrict__ b_ih_l,   // 2 x 512
    const float* __restrict__ b_hh_l,   // 2 x 512
    float* __restrict__ xproj)          // 2 x 32768 x 512
{
    const int d  = blockIdx.z;
    const float* W = w_ih_l + (size_t)d * G4 * INF;
    float* C = xproj + (size_t)d * 32768 * 512;
    const int m0 = blockIdx.y * 128;
    const int n0 = blockIdx.x * 128;
    const int tid = threadIdx.x;
    const int tx = tid & 15, ty = tid >> 4;

    __shared__ __align__(16) float As[16 * 132];
    __shared__ __align__(16) float Bs[16 * 132];

    float acc[8][8] = {};
    const int lr = tid >> 1;        // 0..127 : row for staging
    const int lk = (tid & 1) * 8;   // k offset for staging (8 floats/thread)

    float4 a0 = *(const float4*)(A + (size_t)(m0 + lr) * 256 + lk);
    float4 a1 = *(const float4*)(A + (size_t)(m0 + lr) * 256 + lk + 4);
    float4 b0 = *(const float4*)(W + (size_t)(n0 + lr) * 256 + lk);
    float4 b1 = *(const float4*)(W + (size_t)(n0 + lr) * 256 + lk + 4);

    for (int k0 = 0; k0 < 256; k0 += 16) {
        __syncthreads();
        As[(lk + 0) * 132 + lr] = a0.x; As[(lk + 1) * 132 + lr] = a0.y;
        As[(lk + 2) * 132 + lr] = a0.z; As[(lk + 3) * 132 + lr] = a0.w;
        As[(lk + 4) * 132 + lr] = a1.x; As[(lk + 5) * 132 + lr] = a1.y;
        As[(lk + 6) * 132 + lr] = a1.z; As[(lk + 7) * 132 + lr] = a1.w;
        Bs[(lk + 0) * 132 + lr] = b0.x; Bs[(lk + 1) * 132 + lr] = b0.y;
        Bs[(lk + 2) * 132 + lr] = b0.z; Bs[(lk + 3) * 132 + lr] = b0.w;
        Bs[(lk + 4) * 132 + lr] = b1.x; Bs[(lk + 5) * 132 + lr] = b1.y;
        Bs[(lk + 6) * 132 + lr] = b1.z; Bs[(lk + 7) * 132 + lr] = b1.w;
        __syncthreads();
        if (k0 + 16 < 256) {   // in flight during the FMA block
            a0 = *(const float4*)(A + (size_t)(m0 + lr) * 256 + k0 + 16 + lk);
            a1 = *(const float4*)(A + (size_t)(m0 + lr) * 256 + k0 + 16 + lk + 4);
            b0 = *(const float4*)(W + (size_t)(n0 + lr) * 256 + k0 + 16 + lk);
            b1 = *(const float4*)(W + (size_t)(n0 + lr) * 256 + k0 + 16 + lk + 4);
        }
#pragma unroll
        for (int kk = 0; kk < 16; ++kk) {
            float4 av0 = *(const float4*)&As[kk * 132 + ty * 4];
            float4 av1 = *(const float4*)&As[kk * 132 + 64 + ty * 4];
            float4 bv0 = *(const float4*)&Bs[kk * 132 + tx * 4];
            float4 bv1 = *(const float4*)&Bs[kk * 132 + 64 + tx * 4];
            float ar[8] = {av0.x, av0.y, av0.z, av0.w, av1.x, av1.y, av1.z, av1.w};
            float br[8] = {bv0.x, bv0.y, bv0.z, bv0.w, bv1.x, bv1.y, bv1.z, bv1.w};
#pragma unroll
            for (int i = 0; i < 8; ++i)
#pragma unroll
                for (int j = 0; j < 8; ++j)
                    acc[i][j] += ar[i] * br[j];
        }
    }

    float bias[8];
#pragma unroll
    for (int j = 0; j < 8; ++j) {
        const int n = n0 + (j < 4 ? tx * 4 + j : 64 + tx * 4 + (j - 4));
        bias[j] = b_ih_l[d * G4 + n] + b_hh_l[d * G4 + n];
    }
#pragma unroll
    for (int i = 0; i < 8; ++i) {
        const int m = m0 + (i < 4 ? ty * 4 + i : 64 + ty * 4 + (i - 4));
        float4 o0, o1;
        o0.x = acc[i][0] + bias[0]; o0.y = acc[i][1] + bias[1];
        o0.z = acc[i][2] + bias[2]; o0.w = acc[i][3] + bias[3];
        o1.x = acc[i][4] + bias[4]; o1.y = acc[i][5] + bias[5];
        o1.z = acc[i][6] + bias[6]; o1.w = acc[i][7] + bias[7];
        *(float4*)(C + (size_t)m * 512 + n0 + tx * 4)      = o0;
        *(float4*)(C + (size_t)m * 512 + n0 + 64 + tx * 4) = o1;
    }
}

// =============== LSTM recurrence v6: 512 threads, one j per quad ===============
// Lane l of wave w: s = l&3 (k-slice AND gate id), g = l>>2, j = 16w + g.
// The quad computes all 4 gate-rows of element j, split over k-slices of 32.
// Per-lane weights: 4 rows x 32 k in f16 = 64 VGPRs -> everything fits in the
// arch VGPR file (no AGPR round-trip, which capped r5 at ~1500 cyc/step).
__global__ __launch_bounds__(512, 2) void lstm_rec(
    const float* __restrict__ xproj,   // 2 x B x T x 512
    const float* __restrict__ w_hh_l,  // 2 x 512 x 128 (this layer's slice)
    float* __restrict__ out)           // B x T x 256  ([fwd|bwd] concat)
{
    const int b = blockIdx.x & 31;
    const int d = blockIdx.x >> 5;
    const int tid = threadIdx.x;
    const int wvid = tid >> 6;
    const int l = tid & 63;
    const int s = l & 3;              // k-slice / gate id
    const int g = l >> 2;             // 0..15
    const int j = (wvid << 4) | g;    // 0..127 : h element owned by this quad

    __shared__ __align__(16) _Float16 hs[HH];            // h in f16
    __shared__ __align__(16) float xbuf[2][CH * 512];    // 2 x 32 KB staged x
    __shared__ __align__(16) float obuf[CH * HH];        // 8 KB h output buffer

    // ---- weights: gate-rows 128G + j, k in [32s, 32s+32), as f16 ----
    half2_t wv[4][16];
#pragma unroll
    for (int G = 0; G < 4; ++G) {
        const float* wr = w_hh_l + (size_t)(d * G4 + 128 * G + j) * HH + 32 * s;
#pragma unroll
        for (int q4 = 0; q4 < 8; ++q4) {
            float4 f = *(const float4*)(wr + 4 * q4);
            wv[G][2 * q4]     = half2_t{(_Float16)f.x, (_Float16)f.y};
            wv[G][2 * q4 + 1] = half2_t{(_Float16)f.z, (_Float16)f.w};
        }
    }

    if (tid < 64) ((half2_t*)hs)[tid] = half2_t{(_Float16)0.f, (_Float16)0.f};
    float c = 0.f;

    const float* xp = xproj + ((size_t)d * BB + b) * TT * 512;
    float* ob = out + (size_t)b * TT * 256 + d * HH;

    // ---- stage chunk 0 into buf 0 via async global->LDS ----
    {
        const int tlo = d ? 1008 : 0;
        const float* gsrc = xp + (size_t)tlo * 512;
#pragma unroll
        for (int i = 0; i < 4; ++i)
            __builtin_amdgcn_global_load_lds((glb_u32*)(gsrc + tid * 4 + i * 2048),
                                             (lds_u32*)&xbuf[0][tid * 4 + i * 2048],
                                             16, 0, 0);
    }
    __syncthreads();   // drains vmcnt -> buf0 ready; hs init visible

    for (int ck = 0; ck < 64; ++ck) {
        const int cur = ck & 1;
        // async prefetch next chunk (stays in flight across lgkm-only barriers)
        if (ck + 1 < 64) {
            const int tlo = d ? (1008 - (ck + 1) * CH) : (ck + 1) * CH;
            const float* gsrc = xp + (size_t)tlo * 512;
#pragma unroll
            for (int i = 0; i < 4; ++i)
                __builtin_amdgcn_global_load_lds((glb_u32*)(gsrc + tid * 4 + i * 2048),
                                                 (lds_u32*)&xbuf[cur ^ 1][tid * 4 + i * 2048],
                                                 16, 0, 0);
        }
        const float* xb = xbuf[cur];

#pragma unroll 1
        for (int si = 0; si < CH; ++si) {
            const int lds_t = d ? (CH - 1 - si) : si;

            // h slice: 64 B (h[32s .. 32s+32)) as 4 x b128
            const float4* hp = (const float4*)(hs + 32 * s);
            float4 hA = hp[0], hB = hp[1], hC = hp[2], hD = hp[3];
            half2_t hh[16];
            hh[0]  = __builtin_bit_cast(half2_t, hA.x);
            hh[1]  = __builtin_bit_cast(half2_t, hA.y);
            hh[2]  = __builtin_bit_cast(half2_t, hA.z);
            hh[3]  = __builtin_bit_cast(half2_t, hA.w);
            hh[4]  = __builtin_bit_cast(half2_t, hB.x);
            hh[5]  = __builtin_bit_cast(half2_t, hB.y);
            hh[6]  = __builtin_bit_cast(half2_t, hB.z);
            hh[7]  = __builtin_bit_cast(half2_t, hB.w);
            hh[8]  = __builtin_bit_cast(half2_t, hC.x);
            hh[9]  = __builtin_bit_cast(half2_t, hC.y);
            hh[10] = __builtin_bit_cast(half2_t, hC.z);
            hh[11] = __builtin_bit_cast(half2_t, hC.w);
            hh[12] = __builtin_bit_cast(half2_t, hD.x);
            hh[13] = __builtin_bit_cast(half2_t, hD.y);
            hh[14] = __builtin_bit_cast(half2_t, hD.z);
            hh[15] = __builtin_bit_cast(half2_t, hD.w);

            float a0 = 0.f, a1 = 0.f, a2 = 0.f, a3 = 0.f;
#pragma unroll
            for (int kk = 0; kk < 16; ++kk) {
                a0 = fdot2f(wv[0][kk], hh[kk], a0);
                a1 = fdot2f(wv[1][kk], hh[kk], a1);
                a2 = fdot2f(wv[2][kk], hh[kk], a2);
                a3 = fdot2f(wv[3][kk], hh[kk], a3);
            }

            // quad butterfly over k-slices via DPP: full sums on all 4 lanes
            a0 += dpp_xor1(a0); a0 += dpp_xor2(a0);
            a1 += dpp_xor1(a1); a1 += dpp_xor2(a1);
            a2 += dpp_xor1(a2); a2 += dpp_xor2(a2);
            a3 += dpp_xor1(a3); a3 += dpp_xor2(a3);

            // lane s takes gate s; add x-preact for row 128s + j
            const float xv = xb[lds_t * 512 + 128 * s + j];
            const float pre = (s == 0 ? a0 : s == 1 ? a1 : s == 2 ? a2 : a3) + xv;

            // activation: gate s (0:i sig, 1:f sig, 2:g tanh, 3:o sig)
            const bool isG = (s == 2);
            const float e = __expf(isG ? 2.f * pre : -pre);
            const float r = rcpf(1.f + e);
            const float v = isG ? 1.f - 2.f * r : r;

            // DPP xor2: s=0 gets tanh(g), s=1 gets sig(o)
            const float t = dpp_xor2(v);
            // DPP xor1: s=1 gets sig(i)*tanh(g) (computed on s=0)
            const float u = dpp_xor1(v * t);

            if (s == 1) {   // c-owner: v=sig(f), t=sig(o), u=sig(i)*tanh(g)
                c = v * c + u;
                const float th = 1.f - 2.f * rcpf(1.f + __expf(2.f * c));
                const float h = t * th;
                hs[j] = (_Float16)h;
                obuf[si * HH + j] = h;
            }
            bar_lgkm();   // lgkmcnt-only barrier: prefetch stays in flight
        }

        // flush obuf for chunk ck (coalesced, 4 floats/thread)
        {
            const int idx = tid * 4;
            const int sf = idx >> 7, jf = idx & 127;
            const int sg = ck * CH + sf;
            const int t  = d ? (TT - 1 - sg) : sg;
            float4 o0 = *(const float4*)&obuf[idx];
            *(float4*)&ob[(size_t)t * 256 + jf] = o0;
        }
        __syncthreads();   // full drain: next-chunk data arrived, obuf reads done
    }
}

// =============== Attention (last-row only) + FC ===============
__global__ __launch_bounds__(256) void attn_kernel(
    const float* __restrict__ out1,  // B x T x 256
    const float* __restrict__ wq, const float* __restrict__ bq,
    const float* __restrict__ wk,
    const float* __restrict__ wv, const float* __restrict__ bv,
    const float* __restrict__ wfc, const float* __restrict__ bfc,
    float* __restrict__ outp)        // B x 4
{
    const int b = blockIdx.x;
    const int tid = threadIdx.x;
    __shared__ float xl[256], q[256], u[256], cx[256];
    __shared__ __align__(16) float r[256];
    __shared__ float sc[TT];
    __shared__ float red[256];

    const float* ob = out1 + (size_t)b * TT * 256;

    xl[tid] = ob[(size_t)(TT - 1) * 256 + tid];
    __syncthreads();

    float acc = bq[tid];
    const float* wqr = wq + (size_t)tid * 256;
#pragma unroll 4
    for (int k = 0; k < 256; ++k) acc += xl[k] * wqr[k];
    q[tid] = acc;
    __syncthreads();

    acc = 0.f;
#pragma unroll 4
    for (int dd = 0; dd < 256; ++dd) acc += q[dd] * wk[(size_t)dd * 256 + tid];
    r[tid] = acc;
    __syncthreads();

    const int wave = tid >> 6, lane = tid & 63;
    float4 r4 = *(const float4*)&r[lane * 4];
    for (int t = wave; t < TT; t += 4) {
        float4 o4 = *(const float4*)(ob + (size_t)t * 256 + lane * 4);
        float p = r4.x * o4.x + r4.y * o4.y + r4.z * o4.z + r4.w * o4.w;
#pragma unroll
        for (int off = 32; off > 0; off >>= 1) p += __shfl_down(p, off, 64);
        if (lane == 0) sc[t] = p * 0.0625f;
    }
    __syncthreads();

    float mx = -1e30f;
#pragma unroll
    for (int i = 0; i < 4; ++i) mx = fmaxf(mx, sc[tid + 256 * i]);
    red[tid] = mx; __syncthreads();
    for (int st = 128; st > 0; st >>= 1) {
        if (tid < st) red[tid] = fmaxf(red[tid], red[tid + st]);
        __syncthreads();
    }
    mx = red[0]; __syncthreads();
    float lsum = 0.f;
#pragma unroll
    for (int i = 0; i < 4; ++i) {
        float e = expf(sc[tid + 256 * i] - mx);
        sc[tid + 256 * i] = e;
        lsum += e;
    }
    __syncthreads();
    red[tid] = lsum; __syncthreads();
    for (int st = 128; st > 0; st >>= 1) {
        if (tid < st) red[tid] += red[tid + st];
        __syncthreads();
    }
    const float inv = 1.f / red[0];
    __syncthreads();

    acc = 0.f;
#pragma unroll 8
    for (int t = 0; t < TT; ++t) acc += sc[t] * ob[(size_t)t * 256 + tid];
    u[tid] = acc * inv;
    __syncthreads();

    acc = bv[tid];
#pragma unroll 4
    for (int k = 0; k < 256; ++k) acc += u[k] * wv[(size_t)tid * 256 + k];
    cx[tid] = acc;
    __syncthreads();

    if (tid < 4) {
        float o = bfc[tid];
        for (int k = 0; k < 256; ++k) o += cx[k] * wfc[tid * 256 + k];
        outp[b * 4 + tid] = o;
    }
}

extern "C" void kernel_launch(void* const* d_in, const int* in_sizes, int n_in,
                              void* d_out, int out_size, void* d_ws, size_t ws_size,
                              hipStream_t stream)
{
    const float* x    = (const float*)d_in[0];
    const float* w_ih = (const float*)d_in[1];
    const float* w_hh = (const float*)d_in[2];
    const float* b_ih = (const float*)d_in[3];
    const float* b_hh = (const float*)d_in[4];
    const float* wq   = (const float*)d_in[5];
    const float* wk   = (const float*)d_in[6];
    const float* wv   = (const float*)d_in[7];
    const float* bq   = (const float*)d_in[8];
    const float* bv   = (const float*)d_in[10];
    const float* wfc  = (const float*)d_in[11];
    const float* bfcv = (const float*)d_in[12];
    float* outp = (float*)d_out;

    float* ws    = (float*)d_ws;
    float* xproj = ws;                        // 2*32768*512 floats (128 MB)
    float* out0  = ws + 33554432;             // 8,388,608 floats (32 MB)
    float* out1  = out0 + 8388608;            // 8,388,608 floats (32 MB)

    dim3 gg(4, 256, 2);   // 128x128 tiles

    gemm_inproj<<<gg, 256, 0, stream>>>(x, w_ih, b_ih, b_hh, xproj);
    lstm_rec<<<64, 512, 0, stream>>>(xproj, w_hh, out0);
    gemm_inproj<<<gg, 256, 0, stream>>>(out0, w_ih + 2 * 512 * 256, b_ih + 1024, b_hh + 1024, xproj);
    lstm_rec<<<64, 512, 0, stream>>>(xproj, w_hh + 2 * 512 * 128, out1);
    attn_kernel<<<32, 256, 0, stream>>>(out1, wq, bq, wk, wv, bv, wfc, bfcv, outp);
}

// Round 7
// 1783.364 us; speedup vs baseline: 1.3465x; 1.0660x over previous
//
#include <hip/hip_runtime.h>
#include <math.h>
#include <stdint.h>

#define BB 32
#define TT 1024
#define INF 256
#define HH 128
#define G4 512   // 4*H
#define CH 16    // LSTM steps per LDS chunk

typedef _Float16 half2_t __attribute__((ext_vector_type(2)));
typedef __attribute__((address_space(3))) uint32_t lds_u32;
typedef __attribute__((address_space(1))) const uint32_t glb_u32;

__device__ __forceinline__ float fdot2f(half2_t a, half2_t b, float c) {
    return __builtin_amdgcn_fdot2(a, b, c, false);
}
__device__ __forceinline__ float rcpf(float x) {
    return __builtin_amdgcn_rcpf(x);
}
// quad_perm DPP moves: VALU pipe, no LDS traffic
__device__ __forceinline__ float dpp_xor1(float x) {
    return __builtin_bit_cast(float, __builtin_amdgcn_update_dpp(
        0, __builtin_bit_cast(int, x), 0xB1, 0xF, 0xF, true));
}
__device__ __forceinline__ float dpp_xor2(float x) {
    return __builtin_bit_cast(float, __builtin_amdgcn_update_dpp(
        0, __builtin_bit_cast(int, x), 0x4E, 0xF, 0xF, true));
}
// workgroup barrier draining ONLY lgkmcnt — keeps async global->LDS prefetch in flight
__device__ __forceinline__ void bar_lgkm() {
    asm volatile("s_waitcnt lgkmcnt(0)\n\ts_barrier" ::: "memory");
}

// =============== GEMM v7: f16 inputs + v_dot2, 128x128 tile, BK=32 ===============
// fp32 path was LDS-read-bound (64 ds_read_b128/wave per k0 vs 4096 VALU cyc).
// f16 halves LDS traffic and doubles MACs/instr -> VALU-bound.
// LDS layout: As2[kp][m] = half2(A[2kp][m], A[2kp+1][m]) -- k-pairs for dot2.
__global__ __launch_bounds__(256, 2) void gemm_inproj(
    const float* __restrict__ A,        // 32768 x 256
    const float* __restrict__ w_ih_l,   // 2 x 512 x 256  (this layer's slice)
    const float* __restrict__ b_ih_l,   // 2 x 512
    const float* __restrict__ b_hh_l,   // 2 x 512
    float* __restrict__ xproj)          // 2 x 32768 x 512
{
    const int d  = blockIdx.z;
    const float* W = w_ih_l + (size_t)d * G4 * INF;
    float* C = xproj + (size_t)d * 32768 * 512;
    const int m0 = blockIdx.y * 128;
    const int n0 = blockIdx.x * 128;
    const int tid = threadIdx.x;
    const int tx = tid & 15, ty = tid >> 4;

    __shared__ __align__(16) half2_t As2[16 * 128];   // 8 KB
    __shared__ __align__(16) half2_t Bs2[16 * 128];   // 8 KB

    float acc[8][8] = {};
    const int lr = tid >> 1;         // 0..127 : row for staging
    const int lk = (tid & 1) * 16;   // k offset for staging (16 floats/thread)

    float4 ar4[4], br4[4];
#pragma unroll
    for (int i = 0; i < 4; ++i) {
        ar4[i] = *(const float4*)(A + (size_t)(m0 + lr) * 256 + lk + 4 * i);
        br4[i] = *(const float4*)(W + (size_t)(n0 + lr) * 256 + lk + 4 * i);
    }

    for (int k0 = 0; k0 < 256; k0 += 32) {
        __syncthreads();
#pragma unroll
        for (int i = 0; i < 4; ++i) {
            const int kp = (lk >> 1) + 2 * i;   // k-pair index
            As2[(kp + 0) * 128 + lr] = half2_t{(_Float16)ar4[i].x, (_Float16)ar4[i].y};
            As2[(kp + 1) * 128 + lr] = half2_t{(_Float16)ar4[i].z, (_Float16)ar4[i].w};
            Bs2[(kp + 0) * 128 + lr] = half2_t{(_Float16)br4[i].x, (_Float16)br4[i].y};
            Bs2[(kp + 1) * 128 + lr] = half2_t{(_Float16)br4[i].z, (_Float16)br4[i].w};
        }
        __syncthreads();
        if (k0 + 32 < 256) {   // in flight during the dot block
#pragma unroll
            for (int i = 0; i < 4; ++i) {
                ar4[i] = *(const float4*)(A + (size_t)(m0 + lr) * 256 + k0 + 32 + lk + 4 * i);
                br4[i] = *(const float4*)(W + (size_t)(n0 + lr) * 256 + k0 + 32 + lk + 4 * i);
            }
        }
#pragma unroll
        for (int kp = 0; kp < 16; ++kp) {
            half2_t av[8], bv[8];
            *(float4*)&av[0] = *(const float4*)&As2[kp * 128 + ty * 4];
            *(float4*)&av[4] = *(const float4*)&As2[kp * 128 + 64 + ty * 4];
            *(float4*)&bv[0] = *(const float4*)&Bs2[kp * 128 + tx * 4];
            *(float4*)&bv[4] = *(const float4*)&Bs2[kp * 128 + 64 + tx * 4];
#pragma unroll
            for (int i = 0; i < 8; ++i)
#pragma unroll
                for (int j = 0; j < 8; ++j)
                    acc[i][j] = fdot2f(av[i], bv[j], acc[i][j]);
        }
    }

    float bias[8];
#pragma unroll
    for (int j = 0; j < 8; ++j) {
        const int n = n0 + (j < 4 ? tx * 4 + j : 64 + tx * 4 + (j - 4));
        bias[j] = b_ih_l[d * G4 + n] + b_hh_l[d * G4 + n];
    }
#pragma unroll
    for (int i = 0; i < 8; ++i) {
        const int m = m0 + (i < 4 ? ty * 4 + i : 64 + ty * 4 + (i - 4));
        float4 o0, o1;
        o0.x = acc[i][0] + bias[0]; o0.y = acc[i][1] + bias[1];
        o0.z = acc[i][2] + bias[2]; o0.w = acc[i][3] + bias[3];
        o1.x = acc[i][4] + bias[4]; o1.y = acc[i][5] + bias[5];
        o1.z = acc[i][6] + bias[6]; o1.w = acc[i][7] + bias[7];
        *(float4*)(C + (size_t)m * 512 + n0 + tx * 4)      = o0;
        *(float4*)(C + (size_t)m * 512 + n0 + 64 + tx * 4) = o1;
    }
}

// =============== LSTM recurrence v7 ===============
// 512 threads; lane l of wave w: s=l&3 (k-slice), j = 16w + (l>>2).
// Quad computes all 4 gate-rows of element j over 32-k slices; DPP butterfly
// gives every lane ALL four reduced preacts; each lane then redundantly
// computes activations + c + h (replicated fp32 state -> identical values),
// removing the route-DPP stages and divergence from the serial chain.
// Dot chains split depth-16 -> 2 x depth-8 to halve dependent-latency.
__global__ __launch_bounds__(512, 1) void lstm_rec(
    const float* __restrict__ xproj,   // 2 x B x T x 512
    const float* __restrict__ w_hh_l,  // 2 x 512 x 128 (this layer's slice)
    float* __restrict__ out)           // B x T x 256  ([fwd|bwd] concat)
{
    const int b = blockIdx.x & 31;
    const int d = blockIdx.x >> 5;
    const int tid = threadIdx.x;
    const int wvid = tid >> 6;
    const int l = tid & 63;
    const int s = l & 3;              // k-slice
    const int g = l >> 2;             // 0..15
    const int j = (wvid << 4) | g;    // 0..127 : h element owned by this quad

    __shared__ __align__(16) _Float16 hs[HH];            // h in f16
    __shared__ __align__(16) float xbuf[2][CH * 512];    // 2 x 32 KB staged x
    __shared__ __align__(16) float obuf[CH * HH];        // 8 KB h output buffer

    // ---- weights: gate-rows 128G + j, k in [32s, 32s+32), as f16 ----
    half2_t wv[4][16];
#pragma unroll
    for (int G = 0; G < 4; ++G) {
        const float* wr = w_hh_l + (size_t)(d * G4 + 128 * G + j) * HH + 32 * s;
#pragma unroll
        for (int q4 = 0; q4 < 8; ++q4) {
            float4 f = *(const float4*)(wr + 4 * q4);
            wv[G][2 * q4]     = half2_t{(_Float16)f.x, (_Float16)f.y};
            wv[G][2 * q4 + 1] = half2_t{(_Float16)f.z, (_Float16)f.w};
        }
    }

    if (tid < 64) ((half2_t*)hs)[tid] = half2_t{(_Float16)0.f, (_Float16)0.f};
    float c = 0.f;   // replicated across the quad

    const float* xp = xproj + ((size_t)d * BB + b) * TT * 512;
    float* ob = out + (size_t)b * TT * 256 + d * HH;

    // ---- stage chunk 0 into buf 0 via async global->LDS ----
    {
        const int tlo = d ? 1008 : 0;
        const float* gsrc = xp + (size_t)tlo * 512;
#pragma unroll
        for (int i = 0; i < 4; ++i)
            __builtin_amdgcn_global_load_lds((glb_u32*)(gsrc + tid * 4 + i * 2048),
                                             (lds_u32*)&xbuf[0][tid * 4 + i * 2048],
                                             16, 0, 0);
    }
    __syncthreads();   // drains vmcnt -> buf0 ready; hs init visible

    for (int ck = 0; ck < 64; ++ck) {
        const int cur = ck & 1;
        if (ck + 1 < 64) {
            const int tlo = d ? (1008 - (ck + 1) * CH) : (ck + 1) * CH;
            const float* gsrc = xp + (size_t)tlo * 512;
#pragma unroll
            for (int i = 0; i < 4; ++i)
                __builtin_amdgcn_global_load_lds((glb_u32*)(gsrc + tid * 4 + i * 2048),
                                                 (lds_u32*)&xbuf[cur ^ 1][tid * 4 + i * 2048],
                                                 16, 0, 0);
        }
        const float* xb = xbuf[cur];

#pragma unroll 1
        for (int si = 0; si < CH; ++si) {
            const int lds_t = d ? (CH - 1 - si) : si;

            // x-preacts for all 4 gates of element j (h-independent: issue first)
            const float xi = xb[lds_t * 512 +       j];
            const float xf = xb[lds_t * 512 + 128 + j];
            const float xg = xb[lds_t * 512 + 256 + j];
            const float xo = xb[lds_t * 512 + 384 + j];

            // h slice: 64 B (h[32s .. 32s+32)) as 4 x b128
            const float4* hp = (const float4*)(hs + 32 * s);
            float4 hA = hp[0], hB = hp[1], hC = hp[2], hD = hp[3];
            half2_t hh[16];
            hh[0]  = __builtin_bit_cast(half2_t, hA.x);
            hh[1]  = __builtin_bit_cast(half2_t, hA.y);
            hh[2]  = __builtin_bit_cast(half2_t, hA.z);
            hh[3]  = __builtin_bit_cast(half2_t, hA.w);
            hh[4]  = __builtin_bit_cast(half2_t, hB.x);
            hh[5]  = __builtin_bit_cast(half2_t, hB.y);
            hh[6]  = __builtin_bit_cast(half2_t, hB.z);
            hh[7]  = __builtin_bit_cast(half2_t, hB.w);
            hh[8]  = __builtin_bit_cast(half2_t, hC.x);
            hh[9]  = __builtin_bit_cast(half2_t, hC.y);
            hh[10] = __builtin_bit_cast(half2_t, hC.z);
            hh[11] = __builtin_bit_cast(half2_t, hC.w);
            hh[12] = __builtin_bit_cast(half2_t, hD.x);
            hh[13] = __builtin_bit_cast(half2_t, hD.y);
            hh[14] = __builtin_bit_cast(half2_t, hD.z);
            hh[15] = __builtin_bit_cast(half2_t, hD.w);

            // split accumulators: 2 x depth-8 chains per gate
            float a0 = 0.f, a1 = 0.f, a2 = 0.f, a3 = 0.f;
            float e0 = 0.f, e1 = 0.f, e2 = 0.f, e3 = 0.f;
#pragma unroll
            for (int kk = 0; kk < 8; ++kk) {
                a0 = fdot2f(wv[0][kk], hh[kk], a0);
                a1 = fdot2f(wv[1][kk], hh[kk], a1);
                a2 = fdot2f(wv[2][kk], hh[kk], a2);
                a3 = fdot2f(wv[3][kk], hh[kk], a3);
                e0 = fdot2f(wv[0][kk + 8], hh[kk + 8], e0);
                e1 = fdot2f(wv[1][kk + 8], hh[kk + 8], e1);
                e2 = fdot2f(wv[2][kk + 8], hh[kk + 8], e2);
                e3 = fdot2f(wv[3][kk + 8], hh[kk + 8], e3);
            }
            a0 += e0; a1 += e1; a2 += e2; a3 += e3;

            // quad butterfly over k-slices via DPP: full sums on all 4 lanes
            a0 += dpp_xor1(a0); a0 += dpp_xor2(a0);
            a1 += dpp_xor1(a1); a1 += dpp_xor2(a1);
            a2 += dpp_xor1(a2); a2 += dpp_xor2(a2);
            a3 += dpp_xor1(a3); a3 += dpp_xor2(a3);

            // redundant (replicated) gate math on all quad lanes
            const float gi = rcpf(1.f + __expf(-(a0 + xi)));
            const float gf = rcpf(1.f + __expf(-(a1 + xf)));
            const float gg = 1.f - 2.f * rcpf(1.f + __expf(2.f * (a2 + xg)));
            const float go = rcpf(1.f + __expf(-(a3 + xo)));
            c = gf * c + gi * gg;
            const float th = 1.f - 2.f * rcpf(1.f + __expf(2.f * c));
            const float h = go * th;
            if (s == 0) {
                hs[j] = (_Float16)h;
                obuf[si * HH + j] = h;
            }
            bar_lgkm();   // lgkmcnt-only barrier: prefetch stays in flight
        }

        // flush obuf for chunk ck (coalesced, 4 floats/thread)
        {
            const int idx = tid * 4;
            const int sf = idx >> 7, jf = idx & 127;
            const int sg = ck * CH + sf;
            const int t  = d ? (TT - 1 - sg) : sg;
            float4 o0 = *(const float4*)&obuf[idx];
            *(float4*)&ob[(size_t)t * 256 + jf] = o0;
        }
        __syncthreads();   // full drain: next-chunk data arrived, obuf reads done
    }
}

// =============== Attention (last-row only) + FC ===============
__global__ __launch_bounds__(256) void attn_kernel(
    const float* __restrict__ out1,  // B x T x 256
    const float* __restrict__ wq, const float* __restrict__ bq,
    const float* __restrict__ wk,
    const float* __restrict__ wv, const float* __restrict__ bv,
    const float* __restrict__ wfc, const float* __restrict__ bfc,
    float* __restrict__ outp)        // B x 4
{
    const int b = blockIdx.x;
    const int tid = threadIdx.x;
    __shared__ float xl[256], q[256], u[256], cx[256];
    __shared__ __align__(16) float r[256];
    __shared__ float sc[TT];
    __shared__ float red[256];

    const float* ob = out1 + (size_t)b * TT * 256;

    xl[tid] = ob[(size_t)(TT - 1) * 256 + tid];
    __syncthreads();

    float acc = bq[tid];
    const float* wqr = wq + (size_t)tid * 256;
#pragma unroll 4
    for (int k = 0; k < 256; ++k) acc += xl[k] * wqr[k];
    q[tid] = acc;
    __syncthreads();

    acc = 0.f;
#pragma unroll 4
    for (int dd = 0; dd < 256; ++dd) acc += q[dd] * wk[(size_t)dd * 256 + tid];
    r[tid] = acc;
    __syncthreads();

    const int wave = tid >> 6, lane = tid & 63;
    float4 r4 = *(const float4*)&r[lane * 4];
    for (int t = wave; t < TT; t += 4) {
        float4 o4 = *(const float4*)(ob + (size_t)t * 256 + lane * 4);
        float p = r4.x * o4.x + r4.y * o4.y + r4.z * o4.z + r4.w * o4.w;
#pragma unroll
        for (int off = 32; off > 0; off >>= 1) p += __shfl_down(p, off, 64);
        if (lane == 0) sc[t] = p * 0.0625f;
    }
    __syncthreads();

    float mx = -1e30f;
#pragma unroll
    for (int i = 0; i < 4; ++i) mx = fmaxf(mx, sc[tid + 256 * i]);
    red[tid] = mx; __syncthreads();
    for (int st = 128; st > 0; st >>= 1) {
        if (tid < st) red[tid] = fmaxf(red[tid], red[tid + st]);
        __syncthreads();
    }
    mx = red[0]; __syncthreads();
    float lsum = 0.f;
#pragma unroll
    for (int i = 0; i < 4; ++i) {
        float e = expf(sc[tid + 256 * i] - mx);
        sc[tid + 256 * i] = e;
        lsum += e;
    }
    __syncthreads();
    red[tid] = lsum; __syncthreads();
    for (int st = 128; st > 0; st >>= 1) {
        if (tid < st) red[tid] += red[tid + st];
        __syncthreads();
    }
    const float inv = 1.f / red[0];
    __syncthreads();

    acc = 0.f;
#pragma unroll 8
    for (int t = 0; t < TT; ++t) acc += sc[t] * ob[(size_t)t * 256 + tid];
    u[tid] = acc * inv;
    __syncthreads();

    acc = bv[tid];
#pragma unroll 4
    for (int k = 0; k < 256; ++k) acc += u[k] * wv[(size_t)tid * 256 + k];
    cx[tid] = acc;
    __syncthreads();

    if (tid < 4) {
        float o = bfc[tid];
        for (int k = 0; k < 256; ++k) o += cx[k] * wfc[tid * 256 + k];
        outp[b * 4 + tid] = o;
    }
}

extern "C" void kernel_launch(void* const* d_in, const int* in_sizes, int n_in,
                              void* d_out, int out_size, void* d_ws, size_t ws_size,
                              hipStream_t stream)
{
    const float* x    = (const float*)d_in[0];
    const float* w_ih = (const float*)d_in[1];
    const float* w_hh = (const float*)d_in[2];
    const float* b_ih = (const float*)d_in[3];
    const float* b_hh = (const float*)d_in[4];
    const float* wq   = (const float*)d_in[5];
    const float* wk   = (const float*)d_in[6];
    const float* wv   = (const float*)d_in[7];
    const float* bq   = (const float*)d_in[8];
    const float* bv   = (const float*)d_in[10];
    const float* wfc  = (const float*)d_in[11];
    const float* bfcv = (const float*)d_in[12];
    float* outp = (float*)d_out;

    float* ws    = (float*)d_ws;
    float* xproj = ws;                        // 2*32768*512 floats (128 MB)
    float* out0  = ws + 33554432;             // 8,388,608 floats (32 MB)
    float* out1  = out0 + 8388608;            // 8,388,608 floats (32 MB)

    dim3 gg(4, 256, 2);   // 128x128 tiles

    gemm_inproj<<<gg, 256, 0, stream>>>(x, w_ih, b_ih, b_hh, xproj);
    lstm_rec<<<64, 512, 0, stream>>>(xproj, w_hh, out0);
    gemm_inproj<<<gg, 256, 0, stream>>>(out0, w_ih + 2 * 512 * 256, b_ih + 1024, b_hh + 1024, xproj);
    lstm_rec<<<64, 512, 0, stream>>>(xproj, w_hh + 2 * 512 * 128, out1);
    attn_kernel<<<32, 256, 0, stream>>>(out1, wq, bq, wk, wv, bv, wfc, bfcv, outp);
}